// Round 1
// baseline (442.598 us; speedup 1.0000x reference)
//
#include <hip/hip_runtime.h>

typedef int   i32x4 __attribute__((ext_vector_type(4)));
typedef int   i32x8 __attribute__((ext_vector_type(8)));
typedef float f32x16 __attribute__((ext_vector_type(16)));

#define D_DIM 256
#define LOG2E 1.4426950408889634f
#define LN2   0.6931471805599453f
// Transposed workspace layout: [strip of 128 rows][kc16 0..15][row 0..127][16B]
#define STRIP_BYTES 32768
#define NBLK 16384

#if __has_builtin(__builtin_amdgcn_exp2f)
static __device__ __forceinline__ float exp2_fast(float x) { return __builtin_amdgcn_exp2f(x); }
#else
static __device__ __forceinline__ float exp2_fast(float x) { return __expf(x * LN2); }
#endif
#if __has_builtin(__builtin_amdgcn_logf)
static __device__ __forceinline__ float log2_fast(float x) { return __builtin_amdgcn_logf(x); }
#else
static __device__ __forceinline__ float log2_fast(float x) { return __logf(x) * LOG2E; }
#endif

#if __has_builtin(__builtin_amdgcn_cvt_pk_fp8_f32)
static __device__ __forceinline__ unsigned int pack4_fp8(float a, float b, float c, float d) {
    int v = 0;
    v = __builtin_amdgcn_cvt_pk_fp8_f32(a, b, v, false);
    v = __builtin_amdgcn_cvt_pk_fp8_f32(c, d, v, true);
    return (unsigned int)v;
}
#else
#include <hip/hip_fp8.h>
static __device__ __forceinline__ unsigned char cv1(float x) {
    __hip_fp8_e4m3 f(x);
    union { __hip_fp8_e4m3 f; unsigned char b; } u; u.f = f; return u.b;
}
static __device__ __forceinline__ unsigned int pack4_fp8(float a, float b, float c, float d) {
    return (unsigned int)cv1(a) | ((unsigned int)cv1(b) << 8) |
           ((unsigned int)cv1(c) << 16) | ((unsigned int)cv1(d) << 24);
}
#endif

// K=64 fp8 MFMA (32x32): MX-scaled if available, else 4x K=16 non-scaled.
static __device__ __forceinline__ f32x16 mfma_fp8_32x32_k64(i32x8 a, i32x8 b, f32x16 c) {
#if __has_builtin(__builtin_amdgcn_mfma_scale_f32_32x32x64_f8f6f4)
    return __builtin_amdgcn_mfma_scale_f32_32x32x64_f8f6f4(a, b, c, 0, 0, 0, 127, 0, 127);
#else
    union { i32x8 v; long l[4]; } ua, ub;
    ua.v = a; ub.v = b;
#pragma unroll
    for (int s = 0; s < 4; ++s)
        c = __builtin_amdgcn_mfma_f32_32x32x16_fp8_fp8(ua.l[s], ub.l[s], c, 0, 0, 0);
    return c;
#endif
}

// Kernel 1 (R10 rewrite): L2-normalize fp32 -> fp8 e4m3, k-major strip layout:
// byte(row, k) -> strip(row>>7)*32768 + (k>>4)*2048 + (row&127)*16 + (k&15).
// One ROW per WAVE: lane i loads float4 #i of the row (1 KB coalesced per
// wave instruction — the old q-quarter layout had adjacent lanes 256 B apart,
// 64 distinct cache lines per instruction). Full-wave shfl reduce for the
// norm; each lane packs its own 4 bytes -> one aligned u32 store
// (chunk = lane>>2 at stride 2048; quad-contiguous 16-B segments).
// Also zeroes the last-block-done counter for kernel 2 (stream-ordered).
__global__ __launch_bounds__(256) void norm_cast_kernel(
    const float* __restrict__ img, const float* __restrict__ txt,
    unsigned char* __restrict__ Ab, unsigned char* __restrict__ Bb,
    unsigned int* __restrict__ counter, int N)
{
    if (blockIdx.x == 0 && threadIdx.x == 0) *counter = 0u;

    const int wave = threadIdx.x >> 6;
    const int lane = threadIdx.x & 63;
    int gRow = blockIdx.x * 4 + wave;   // 0..2N-1, wave-uniform

    const float* src;
    unsigned char* dstB;
    int row;
    if (gRow < N) { row = gRow;     src = img + (size_t)row * D_DIM; dstB = Ab; }
    else          { row = gRow - N; src = txt + (size_t)row * D_DIM; dstB = Bb; }

    float4 v = ((const float4*)src)[lane];
    float ss = v.x*v.x + v.y*v.y + v.z*v.z + v.w*v.w;
#pragma unroll
    for (int off = 1; off < 64; off <<= 1)
        ss += __shfl_xor(ss, off, 64);
    float inv = 1.0f / fmaxf(sqrtf(ss), 1e-12f);   // F.normalize eps

    // lane i holds k = 4i..4i+3: chunk = i>>2, byte-in-chunk = (i&3)*4.
    unsigned int w = pack4_fp8(v.x*inv, v.y*inv, v.z*inv, v.w*inv);
    unsigned char* dst = dstB + (size_t)(row >> 7) * STRIP_BYTES
                       + (lane >> 2) * 2048 + (row & 127) * 16 + (lane & 3) * 4;
    *(unsigned int*)dst = w;
}

// Kernel 2: fp8-MX Gram + softplus-sum + inline diag. Core identical to the
// 180-us version; tail now folds the partials reduction in via the
// last-block-done pattern (1 atomic per block, NOT an atomic accumulate —
// 16384 same-address float atomics was the 218-us plateau), removing the
// third kernel launch.
__global__ __launch_bounds__(256, 4) void siglip_loss_kernel(
    const unsigned char* __restrict__ A, const unsigned char* __restrict__ B,
    const float* __restrict__ t_prime, const float* __restrict__ bias,
    float* __restrict__ partials, unsigned int* __restrict__ counter,
    float* __restrict__ out, int N)
{
    __shared__ unsigned char As[2][8192];   // [kc16 0..3][row 0..127][16B]
    __shared__ unsigned char Bs[2][8192];
    __shared__ float red[4];
    __shared__ int isLast;

    const int tid  = threadIdx.x;
    const int wave = tid >> 6;
    const int lane = tid & 63;
    const int r31  = lane & 31;
    const int g    = lane >> 5;       // k-group (2 kc16 chunks of the 4)
    const int wv   = wave >> 1;       // 0..1 row half
    const int wu   = wave & 1;        // 0..1 col half

    // 16x16 supertile swizzle for L2 locality (grid 16384 flat).
    const int bid = blockIdx.x;
    const int st  = bid >> 8;
    const int l2  = bid & 255;
    const int bx  = (st & 7) * 16 + (l2 & 15);
    const int by  = (st >> 3) * 16 + (l2 >> 4);
    const int rowBase = by * 128;
    const int colBase = bx * 128;

    const unsigned char* Astrip = A + (size_t)by * STRIP_BYTES;
    const unsigned char* Bstrip = B + (size_t)bx * STRIP_BYTES;

    // Stage K-chunk c (8 KB per operand = 8 x 1KB loads, 2 per wave each).
    auto stage = [&](int buf, int c) {
        const unsigned char* ga = Astrip + c * 8192;
        const unsigned char* gb = Bstrip + c * 8192;
#pragma unroll
        for (int l = 0; l < 2; ++l) {
            int idx = wave * 2 + l;   // 0..7
            __builtin_amdgcn_global_load_lds(
                (const __attribute__((address_space(1))) unsigned int*)(ga + idx * 1024 + lane * 16),
                (__attribute__((address_space(3))) unsigned int*)&As[buf][idx * 1024],
                16, 0, 0);
            __builtin_amdgcn_global_load_lds(
                (const __attribute__((address_space(1))) unsigned int*)(gb + idx * 1024 + lane * 16),
                (__attribute__((address_space(3))) unsigned int*)&Bs[buf][idx * 1024],
                16, 0, 0);
        }
    };

    stage(0, 0);

    // Fragment LDS offsets: kc_local = 2g (+1 for the second 16B half).
    int a_off[2], b_off[2];
#pragma unroll
    for (int i = 0; i < 2; ++i) a_off[i] = g * 4096 + (wv * 64 + i * 32 + r31) * 16;
#pragma unroll
    for (int j = 0; j < 2; ++j) b_off[j] = g * 4096 + (wu * 64 + j * 32 + r31) * 16;

    f32x16 acc[2][2] = {};
    union F { i32x8 v8; i32x4 v4[2]; };

#pragma unroll 1
    for (int c = 0; c < 4; ++c) {
        __syncthreads();                    // publishes buffer c&1
        if (c < 3) stage((c + 1) & 1, c + 1);

        const unsigned char* as = As[c & 1];
        const unsigned char* bs = Bs[c & 1];
        F a[2], b[2];
#pragma unroll
        for (int i = 0; i < 2; ++i) {
            a[i].v4[0] = *(const i32x4*)&as[a_off[i]];
            a[i].v4[1] = *(const i32x4*)&as[a_off[i] + 2048];
            b[i].v4[0] = *(const i32x4*)&bs[b_off[i]];
            b[i].v4[1] = *(const i32x4*)&bs[b_off[i] + 2048];
        }
#pragma unroll
        for (int i = 0; i < 2; ++i)
#pragma unroll
            for (int j = 0; j < 2; ++j)
                acc[i][j] = mfma_fp8_32x32_k64(a[i].v8, b[j].v8, acc[i][j]);
    }

    // Epilogue: z2 = s2*acc + b2 (log2 domain); log2 of products of 8.
    const float s2 = __expf(t_prime[0]) * LOG2E;
    const float b2 = bias[0] * LOG2E;
    float local = 0.0f;
#pragma unroll
    for (int i = 0; i < 2; ++i)
#pragma unroll
        for (int j = 0; j < 2; ++j)
#pragma unroll
            for (int g2 = 0; g2 < 2; ++g2) {
                float x[8];
#pragma unroll
                for (int e = 0; e < 8; ++e)
                    x[e] = exp2_fast(fmaf(s2, acc[i][j][g2 * 8 + e], b2));
                float p = 1.0f + x[0];
#pragma unroll
                for (int e = 1; e < 8; ++e)
                    p = fmaf(p, x[e], p);      // p *= (1 + x[e])
                local += log2_fast(p);
            }

    // Diagonal blocks: softplus(-z) = softplus(z) - z -> subtract z2.
    if (rowBase == colBase) {
#pragma unroll
        for (int i = 0; i < 2; ++i)
#pragma unroll
            for (int j = 0; j < 2; ++j)
#pragma unroll
                for (int r = 0; r < 16; ++r) {
                    // 32x32 C/D layout (m74/m101): col = lane&31,
                    // row = (r&3) + 8*(r>>2) + 4*(lane>>5)
                    int rowf = (r & 3) + 8 * (r >> 2) + 4 * g;
                    int grow = wv * 64 + i * 32 + rowf;
                    int gcol = wu * 64 + j * 32 + r31;
                    if (grow == gcol) local -= fmaf(s2, acc[i][j][r], b2);
                }
    }

#pragma unroll
    for (int off = 32; off > 0; off >>= 1)
        local += __shfl_xor(local, off, 64);
    if (lane == 0) red[wave] = local;
    __syncthreads();
    if (tid == 0) {
        partials[bid] = (red[0] + red[1]) + (red[2] + red[3]);   // plain store
        __threadfence();                                          // publish partial
        unsigned int old = atomicAdd(counter, 1u);                // device-scope
        isLast = (old == (unsigned int)(NBLK - 1)) ? 1 : 0;
    }
    __syncthreads();

    // Last arriving block reduces all 16384 partials (replaces reduce_kernel).
    if (isLast) {
        __threadfence();    // acquire side: make other blocks' partials visible
        float s = 0.0f;
#pragma unroll 8
        for (int i = tid; i < NBLK; i += 256)
            s += partials[i];
#pragma unroll
        for (int off = 32; off > 0; off >>= 1)
            s += __shfl_xor(s, off, 64);
        if (lane == 0) red[wave] = s;
        __syncthreads();
        if (tid == 0)
            out[0] = ((red[0] + red[1]) + (red[2] + red[3])) * (LN2 / (float)N);
    }
}

extern "C" void kernel_launch(void* const* d_in, const int* in_sizes, int n_in,
                              void* d_out, int out_size, void* d_ws, size_t ws_size,
                              hipStream_t stream) {
    const float* img = (const float*)d_in[0];
    const float* txt = (const float*)d_in[1];
    const float* tp  = (const float*)d_in[2];
    const float* bs  = (const float*)d_in[3];
    float* out = (float*)d_out;
    int N = in_sizes[0] / D_DIM;    // 16384

    unsigned char* Ab = (unsigned char*)d_ws;       // 4 MB (k-major strips)
    unsigned char* Bb = Ab + (size_t)N * D_DIM;     // +4 MB
    float* partials   = (float*)(Bb + (size_t)N * D_DIM);   // 64 KB
    unsigned int* counter = (unsigned int*)(partials + NBLK);

    norm_cast_kernel<<<(2 * N) / 4, 256, 0, stream>>>(img, txt, Ab, Bb, counter, N);
    siglip_loss_kernel<<<NBLK, 256, 0, stream>>>(Ab, Bb, tp, bs, partials, counter, out, N);
}

// Round 2
// 168.529 us; speedup vs baseline: 2.6262x; 2.6262x over previous
//
#include <hip/hip_runtime.h>

typedef int   i32x4 __attribute__((ext_vector_type(4)));
typedef int   i32x8 __attribute__((ext_vector_type(8)));
typedef float f32x16 __attribute__((ext_vector_type(16)));

#define D_DIM 256
#define LOG2E 1.4426950408889634f
#define LN2   0.6931471805599453f
// Transposed workspace layout: [strip of 128 rows][kc16 0..15][row 0..127][16B]
#define STRIP_BYTES 32768
#define NBLK 16384

#if __has_builtin(__builtin_amdgcn_exp2f)
static __device__ __forceinline__ float exp2_fast(float x) { return __builtin_amdgcn_exp2f(x); }
#else
static __device__ __forceinline__ float exp2_fast(float x) { return __expf(x * LN2); }
#endif
#if __has_builtin(__builtin_amdgcn_logf)
static __device__ __forceinline__ float log2_fast(float x) { return __builtin_amdgcn_logf(x); }
#else
static __device__ __forceinline__ float log2_fast(float x) { return __logf(x) * LOG2E; }
#endif

#if __has_builtin(__builtin_amdgcn_cvt_pk_fp8_f32)
static __device__ __forceinline__ unsigned int pack4_fp8(float a, float b, float c, float d) {
    int v = 0;
    v = __builtin_amdgcn_cvt_pk_fp8_f32(a, b, v, false);
    v = __builtin_amdgcn_cvt_pk_fp8_f32(c, d, v, true);
    return (unsigned int)v;
}
#else
#include <hip/hip_fp8.h>
static __device__ __forceinline__ unsigned char cv1(float x) {
    __hip_fp8_e4m3 f(x);
    union { __hip_fp8_e4m3 f; unsigned char b; } u; u.f = f; return u.b;
}
static __device__ __forceinline__ unsigned int pack4_fp8(float a, float b, float c, float d) {
    return (unsigned int)cv1(a) | ((unsigned int)cv1(b) << 8) |
           ((unsigned int)cv1(c) << 16) | ((unsigned int)cv1(d) << 24);
}
#endif

// K=64 fp8 MFMA (32x32): MX-scaled if available, else 4x K=16 non-scaled.
static __device__ __forceinline__ f32x16 mfma_fp8_32x32_k64(i32x8 a, i32x8 b, f32x16 c) {
#if __has_builtin(__builtin_amdgcn_mfma_scale_f32_32x32x64_f8f6f4)
    return __builtin_amdgcn_mfma_scale_f32_32x32x64_f8f6f4(a, b, c, 0, 0, 0, 127, 0, 127);
#else
    union { i32x8 v; long l[4]; } ua, ub;
    ua.v = a; ub.v = b;
#pragma unroll
    for (int s = 0; s < 4; ++s)
        c = __builtin_amdgcn_mfma_f32_32x32x16_fp8_fp8(ua.l[s], ub.l[s], c, 0, 0, 0);
    return c;
#endif
}

// Kernel 1: L2-normalize fp32 -> fp8 e4m3, k-major strip layout:
// byte(row, k) -> strip(row>>7)*32768 + (k>>4)*2048 + (row&127)*16 + (k&15).
// One ROW per WAVE: lane i loads float4 #i of the row (1 KB coalesced per
// wave load instruction — the old q-quarter layout put adjacent lanes 256 B
// apart: 64 distinct cache lines per instruction). Full-wave shfl reduce for
// the norm; each lane packs its own 4 bytes -> one aligned u32 store
// (chunk = lane>>2 at stride 2048; quad-contiguous 16-B segments).
__global__ __launch_bounds__(256) void norm_cast_kernel(
    const float* __restrict__ img, const float* __restrict__ txt,
    unsigned char* __restrict__ Ab, unsigned char* __restrict__ Bb, int N)
{
    const int wave = threadIdx.x >> 6;
    const int lane = threadIdx.x & 63;
    int gRow = blockIdx.x * 4 + wave;   // 0..2N-1, wave-uniform

    const float* src;
    unsigned char* dstB;
    int row;
    if (gRow < N) { row = gRow;     src = img + (size_t)row * D_DIM; dstB = Ab; }
    else          { row = gRow - N; src = txt + (size_t)row * D_DIM; dstB = Bb; }

    float4 v = ((const float4*)src)[lane];
    float ss = v.x*v.x + v.y*v.y + v.z*v.z + v.w*v.w;
#pragma unroll
    for (int off = 1; off < 64; off <<= 1)
        ss += __shfl_xor(ss, off, 64);
    float inv = 1.0f / fmaxf(sqrtf(ss), 1e-12f);   // F.normalize eps

    // lane i holds k = 4i..4i+3: chunk = i>>2, byte-in-chunk = (i&3)*4.
    unsigned int w = pack4_fp8(v.x*inv, v.y*inv, v.z*inv, v.w*inv);
    unsigned char* dst = dstB + (size_t)(row >> 7) * STRIP_BYTES
                       + (lane >> 2) * 2048 + (row & 127) * 16 + (lane & 3) * 4;
    *(unsigned int*)dst = w;
}

// Kernel 2: fp8-MX Gram + softplus-sum + inline diag. Per-block partial is
// STORED (coalesced, contention-free), NOT accumulated or counted via a
// same-address atomic: 16384 same-address device atomics serialize at
// ~13 ns each (~218 us floor; R1's last-block-done atomicAdd(counter)
// regressed to 390 us for the same reason — ANY same-address RMW, not just
// atomic accumulation). The 3-us reduce_kernel is the cheap alternative.
__global__ __launch_bounds__(256, 4) void siglip_loss_kernel(
    const unsigned char* __restrict__ A, const unsigned char* __restrict__ B,
    const float* __restrict__ t_prime, const float* __restrict__ bias,
    float* __restrict__ partials, int N)
{
    __shared__ unsigned char As[2][8192];   // [kc16 0..3][row 0..127][16B]
    __shared__ unsigned char Bs[2][8192];
    __shared__ float red[4];

    const int tid  = threadIdx.x;
    const int wave = tid >> 6;
    const int lane = tid & 63;
    const int r31  = lane & 31;
    const int g    = lane >> 5;       // k-group (2 kc16 chunks of the 4)
    const int wv   = wave >> 1;       // 0..1 row half
    const int wu   = wave & 1;        // 0..1 col half

    // 16x16 supertile swizzle for L2 locality (grid 16384 flat).
    const int bid = blockIdx.x;
    const int st  = bid >> 8;
    const int l2  = bid & 255;
    const int bx  = (st & 7) * 16 + (l2 & 15);
    const int by  = (st >> 3) * 16 + (l2 >> 4);
    const int rowBase = by * 128;
    const int colBase = bx * 128;

    const unsigned char* Astrip = A + (size_t)by * STRIP_BYTES;
    const unsigned char* Bstrip = B + (size_t)bx * STRIP_BYTES;

    // Stage K-chunk c (8 KB per operand = 8 x 1KB loads, 2 per wave each).
    auto stage = [&](int buf, int c) {
        const unsigned char* ga = Astrip + c * 8192;
        const unsigned char* gb = Bstrip + c * 8192;
#pragma unroll
        for (int l = 0; l < 2; ++l) {
            int idx = wave * 2 + l;   // 0..7
            __builtin_amdgcn_global_load_lds(
                (const __attribute__((address_space(1))) unsigned int*)(ga + idx * 1024 + lane * 16),
                (__attribute__((address_space(3))) unsigned int*)&As[buf][idx * 1024],
                16, 0, 0);
            __builtin_amdgcn_global_load_lds(
                (const __attribute__((address_space(1))) unsigned int*)(gb + idx * 1024 + lane * 16),
                (__attribute__((address_space(3))) unsigned int*)&Bs[buf][idx * 1024],
                16, 0, 0);
        }
    };

    stage(0, 0);

    // Fragment LDS offsets: kc_local = 2g (+1 for the second 16B half).
    int a_off[2], b_off[2];
#pragma unroll
    for (int i = 0; i < 2; ++i) a_off[i] = g * 4096 + (wv * 64 + i * 32 + r31) * 16;
#pragma unroll
    for (int j = 0; j < 2; ++j) b_off[j] = g * 4096 + (wu * 64 + j * 32 + r31) * 16;

    f32x16 acc[2][2] = {};
    union F { i32x8 v8; i32x4 v4[2]; };

#pragma unroll 1
    for (int c = 0; c < 4; ++c) {
        __syncthreads();                    // publishes buffer c&1
        if (c < 3) stage((c + 1) & 1, c + 1);

        const unsigned char* as = As[c & 1];
        const unsigned char* bs = Bs[c & 1];
        F a[2], b[2];
#pragma unroll
        for (int i = 0; i < 2; ++i) {
            a[i].v4[0] = *(const i32x4*)&as[a_off[i]];
            a[i].v4[1] = *(const i32x4*)&as[a_off[i] + 2048];
            b[i].v4[0] = *(const i32x4*)&bs[b_off[i]];
            b[i].v4[1] = *(const i32x4*)&bs[b_off[i] + 2048];
        }
#pragma unroll
        for (int i = 0; i < 2; ++i)
#pragma unroll
            for (int j = 0; j < 2; ++j)
                acc[i][j] = mfma_fp8_32x32_k64(a[i].v8, b[j].v8, acc[i][j]);
    }

    // Epilogue: z2 = s2*acc + b2 (log2 domain); log2 of products of 8.
    const float s2 = __expf(t_prime[0]) * LOG2E;
    const float b2 = bias[0] * LOG2E;
    float local = 0.0f;
#pragma unroll
    for (int i = 0; i < 2; ++i)
#pragma unroll
        for (int j = 0; j < 2; ++j)
#pragma unroll
            for (int g2 = 0; g2 < 2; ++g2) {
                float x[8];
#pragma unroll
                for (int e = 0; e < 8; ++e)
                    x[e] = exp2_fast(fmaf(s2, acc[i][j][g2 * 8 + e], b2));
                float p = 1.0f + x[0];
#pragma unroll
                for (int e = 1; e < 8; ++e)
                    p = fmaf(p, x[e], p);      // p *= (1 + x[e])
                local += log2_fast(p);
            }

    // Diagonal blocks: softplus(-z) = softplus(z) - z -> subtract z2.
    if (rowBase == colBase) {
#pragma unroll
        for (int i = 0; i < 2; ++i)
#pragma unroll
            for (int j = 0; j < 2; ++j)
#pragma unroll
                for (int r = 0; r < 16; ++r) {
                    // 32x32 C/D layout (m74/m101): col = lane&31,
                    // row = (r&3) + 8*(r>>2) + 4*(lane>>5)
                    int rowf = (r & 3) + 8 * (r >> 2) + 4 * g;
                    int grow = wv * 64 + i * 32 + rowf;
                    int gcol = wu * 64 + j * 32 + r31;
                    if (grow == gcol) local -= fmaf(s2, acc[i][j][r], b2);
                }
    }

#pragma unroll
    for (int off = 32; off > 0; off >>= 1)
        local += __shfl_xor(local, off, 64);
    if (lane == 0) red[wave] = local;
    __syncthreads();
    if (tid == 0)
        partials[bid] = (red[0] + red[1]) + (red[2] + red[3]);   // plain store
}

// Kernel 3: reduce 16384 per-block partials -> out[0]. One block, ~3 us.
__global__ __launch_bounds__(1024) void reduce_kernel(
    const float* __restrict__ partials, float* __restrict__ out, int N)
{
    __shared__ float red[16];
    const int tid  = threadIdx.x;
    const int wave = tid >> 6;
    const int lane = tid & 63;
    float s = 0.0f;
#pragma unroll 4
    for (int i = tid; i < NBLK; i += 1024)
        s += partials[i];
#pragma unroll
    for (int off = 32; off > 0; off >>= 1)
        s += __shfl_xor(s, off, 64);
    if (lane == 0) red[wave] = s;
    __syncthreads();
    if (tid == 0) {
        float t = 0.0f;
#pragma unroll
        for (int w = 0; w < 16; ++w) t += red[w];
        out[0] = t * (LN2 / (float)N);
    }
}

extern "C" void kernel_launch(void* const* d_in, const int* in_sizes, int n_in,
                              void* d_out, int out_size, void* d_ws, size_t ws_size,
                              hipStream_t stream) {
    const float* img = (const float*)d_in[0];
    const float* txt = (const float*)d_in[1];
    const float* tp  = (const float*)d_in[2];
    const float* bs  = (const float*)d_in[3];
    float* out = (float*)d_out;
    int N = in_sizes[0] / D_DIM;    // 16384

    unsigned char* Ab = (unsigned char*)d_ws;       // 4 MB (k-major strips)
    unsigned char* Bb = Ab + (size_t)N * D_DIM;     // +4 MB
    float* partials   = (float*)(Bb + (size_t)N * D_DIM);   // 64 KB

    norm_cast_kernel<<<(2 * N) / 4, 256, 0, stream>>>(img, txt, Ab, Bb, N);
    siglip_loss_kernel<<<NBLK, 256, 0, stream>>>(Ab, Bb, tp, bs, partials, N);
    reduce_kernel<<<1, 1024, 0, stream>>>(partials, out, N);
}